// Round 1
// baseline (127.844 us; speedup 1.0000x reference)
//
#include <hip/hip_runtime.h>
#include <math.h>

#define NB 4
#define NN 256
#define MAT (NN*NN)      // 65536
#define BMAT (NB*MAT)    // 262144
#define ALPHA 0.2f

__device__ __forceinline__ float wave_reduce_sum(float v) {
    #pragma unroll
    for (int o = 32; o > 0; o >>= 1) v += __shfl_down(v, o, 64);
    return v;
}
__device__ __forceinline__ float wave_reduce_max(float v) {
    #pragma unroll
    for (int o = 32; o > 0; o >>= 1) v = fmaxf(v, __shfl_down(v, o, 64));
    return v;
}

// 256-thread block sum; s4 is a 4-float shared buffer
__device__ __forceinline__ float block_sum_256(float v, float* s4) {
    int lane = threadIdx.x & 63, w = threadIdx.x >> 6;
    v = wave_reduce_sum(v);
    if (lane == 0) s4[w] = v;
    __syncthreads();
    float r = s4[0] + s4[1] + s4[2] + s4[3];
    __syncthreads();
    return r;
}

__global__ void k_copy(const float* __restrict__ src, float* __restrict__ dst, int n) {
    int i = blockIdx.x * blockDim.x + threadIdx.x;
    if (i < n) dst[i] = src[i];
}

// S = sum(a_e)  (512 elements)
__global__ void k_sum(const float* __restrict__ a, int n, float* __restrict__ out) {
    __shared__ float s4[4];
    float v = 0.f;
    for (int i = threadIdx.x; i < n; i += 256) v += a[i];
    v = block_sum_256(v, s4);
    if (threadIdx.x == 0) out[0] = v;
}

// C[b,i,j] = sum_m E[b,i,m]*W[m,j] + bias[j]
__global__ void k_gemm_bias(const float* __restrict__ E, const float* __restrict__ W,
                            const float* __restrict__ bias, float* __restrict__ C) {
    __shared__ float As[16][17], Bs[16][17];
    int b = blockIdx.z;
    int tx = threadIdx.x, ty = threadIdx.y;
    int row = blockIdx.y * 16 + ty, col = blockIdx.x * 16 + tx;
    const float* Eb = E + b * MAT;
    float acc = 0.f;
    for (int k0 = 0; k0 < NN; k0 += 16) {
        As[ty][tx] = Eb[row * NN + k0 + tx];
        Bs[ty][tx] = W[(k0 + ty) * NN + col];
        __syncthreads();
        #pragma unroll
        for (int k = 0; k < 16; ++k) acc += As[ty][k] * Bs[k][tx];
        __syncthreads();
    }
    C[b * MAT + row * NN + col] = acc + bias[col];
}

// Adj[b,i,j] = ((sig(G[b,i,j])+sig(G[b,j,i]))*0.5 > 0.5); cnt[b,i] = row count
__global__ void k_adj(const float* __restrict__ G, float* __restrict__ Adj,
                      float* __restrict__ cnt) {
    __shared__ float s4[4];
    int b = blockIdx.y, i = blockIdx.x, j = threadIdx.x;
    float g1 = G[(b * NN + i) * NN + j];
    float g2 = G[(b * NN + j) * NN + i];
    float s = 0.5f * (1.f / (1.f + expf(-g1)) + 1.f / (1.f + expf(-g2)));
    float av = (s > 0.5f) ? 1.f : 0.f;
    Adj[(b * NN + i) * NN + j] = av;
    float c = block_sum_256(av, s4);
    if (j == 0) cnt[b * NN + i] = c;
}

// per (b,k): L = leaky(S*H); M = max_j L; eL = exp(L-M); eH = eL*H; rs = sum_j H
__global__ void k_rowtrans(const float* __restrict__ H, const float* __restrict__ Sp,
                           float* __restrict__ eL, float* __restrict__ eH,
                           float* __restrict__ rs) {
    __shared__ float s4[4];
    int b = blockIdx.y, k = blockIdx.x, j = threadIdx.x;
    float S = Sp[0];
    float h = H[(b * NN + k) * NN + j];
    float x = S * h;
    float L = (x > 0.f) ? x : ALPHA * x;
    int lane = j & 63, w = j >> 6;
    float v = wave_reduce_max(L);
    if (lane == 0) s4[w] = v;
    __syncthreads();
    float M = fmaxf(fmaxf(s4[0], s4[1]), fmaxf(s4[2], s4[3]));
    __syncthreads();
    float e = expf(L - M);
    eL[(b * NN + k) * NN + j] = e;
    eH[(b * NN + k) * NN + j] = e * h;
    float sum = block_sum_256(h, s4);
    if (j == 0) rs[b * NN + k] = sum;
}

// D[b,k,i] = sum_j eL[b,k,j]*Adj[b,i,j];  Num[b,k,i] = sum_j eH[b,k,j]*Adj[b,i,j]
__global__ void k_attn(const float* __restrict__ eL, const float* __restrict__ eH,
                       const float* __restrict__ Adj, float* __restrict__ D,
                       float* __restrict__ Num) {
    __shared__ float Ls[16][17], Hs[16][17], As[16][17];
    int b = blockIdx.z;
    int tx = threadIdx.x, ty = threadIdx.y;
    int k = blockIdx.y * 16 + ty;   // output row
    int i = blockIdx.x * 16 + tx;   // output col
    const float* eLb = eL + b * MAT;
    const float* eHb = eH + b * MAT;
    const float* Ab  = Adj + b * MAT;
    float dacc = 0.f, nacc = 0.f;
    for (int j0 = 0; j0 < NN; j0 += 16) {
        Ls[ty][tx] = eLb[k * NN + j0 + tx];
        Hs[ty][tx] = eHb[k * NN + j0 + tx];
        As[ty][tx] = Ab[(blockIdx.x * 16 + ty) * NN + j0 + tx];
        __syncthreads();
        #pragma unroll
        for (int jj = 0; jj < 16; ++jj) {
            float a = As[tx][jj];
            dacc += Ls[ty][jj] * a;
            nacc += Hs[ty][jj] * a;
        }
        __syncthreads();
    }
    D[b * MAT + k * NN + i] = dacc;
    Num[b * MAT + k * NN + i] = nacc;
}

// E'[b,k,i] = 0.5*(f(k,i)+f(i,k)); f(k,i) = cnt[b,i]>0 ? Num[b,k,i]/D[b,k,i] : rs[b,k]/256
__global__ void k_final(const float* __restrict__ Num, const float* __restrict__ D,
                        const float* __restrict__ cnt, const float* __restrict__ rs,
                        float* __restrict__ E) {
    int idx = blockIdx.x * blockDim.x + threadIdx.x;
    int b = idx >> 16;
    int r = (idx >> 8) & 255;
    int ci = idx & 255;
    int base = b * MAT;
    float f1 = (cnt[b * NN + ci] > 0.5f)
                   ? Num[base + r * NN + ci] / D[base + r * NN + ci]
                   : rs[b * NN + r] * (1.f / 256.f);
    float f2 = (cnt[b * NN + r] > 0.5f)
                   ? Num[base + ci * NN + r] / D[base + ci * NN + r]
                   : rs[b * NN + ci] * (1.f / 256.f);
    E[idx] = 0.5f * (f1 + f2);
}

__global__ void k_tanh(const float* __restrict__ E, float* __restrict__ out) {
    int idx = blockIdx.x * blockDim.x + threadIdx.x;
    float t = tanhf(E[idx]);
    out[idx] = t;
    out[BMAT + idx] = t;   // reference returns (out, out)
}

extern "C" void kernel_launch(void* const* d_in, const int* in_sizes, int n_in,
                              void* d_out, int out_size, void* d_ws, size_t ws_size,
                              hipStream_t stream) {
    const float* edges = (const float*)d_in[1];
    const float* wp[2] = {(const float*)d_in[7],  (const float*)d_in[17]};
    const float* bp[2] = {(const float*)d_in[8],  (const float*)d_in[18]};
    const float* ae[2] = {(const float*)d_in[9],  (const float*)d_in[19]};
    const float* wa[2] = {(const float*)d_in[10], (const float*)d_in[20]};
    const float* ba[2] = {(const float*)d_in[11], (const float*)d_in[21]};

    float* ws  = (float*)d_ws;
    float* E   = ws + 0 * BMAT;
    float* G   = ws + 1 * BMAT;
    float* Adj = ws + 2 * BMAT;
    float* H   = ws + 3 * BMAT;
    float* eL  = ws + 4 * BMAT;
    float* eH  = ws + 5 * BMAT;
    float* D   = ws + 6 * BMAT;
    float* Num = ws + 7 * BMAT;
    float* cnt = ws + 8 * BMAT;        // NB*NN
    float* rs  = cnt + NB * NN;        // NB*NN
    float* Sp  = rs + NB * NN;         // 1

    dim3 gg(16, 16, NB), bb(16, 16);

    k_copy<<<BMAT / 256, 256, 0, stream>>>(edges, E, BMAT);
    for (int l = 0; l < 2; ++l) {
        k_sum<<<1, 256, 0, stream>>>(ae[l], 512, Sp);
        k_gemm_bias<<<gg, bb, 0, stream>>>(E, wa[l], ba[l], G);
        k_gemm_bias<<<gg, bb, 0, stream>>>(E, wp[l], bp[l], H);
        k_adj<<<dim3(NN, NB), 256, 0, stream>>>(G, Adj, cnt);
        k_rowtrans<<<dim3(NN, NB), 256, 0, stream>>>(H, Sp, eL, eH, rs);
        k_attn<<<gg, bb, 0, stream>>>(eL, eH, Adj, D, Num);
        k_final<<<BMAT / 256, 256, 0, stream>>>(Num, D, cnt, rs, E);
    }
    k_tanh<<<BMAT / 256, 256, 0, stream>>>(E, (float*)d_out);
}